// Round 2
// baseline (1209.331 us; speedup 1.0000x reference)
//
#include <hip/hip_runtime.h>
#include <hip/hip_fp8.h>

#define T_DIM 2048
#define D_DIM 4096
#define I_DIM 11008

typedef int v8i __attribute__((ext_vector_type(8)));
typedef int v4i __attribute__((ext_vector_type(4)));
typedef float v4f __attribute__((ext_vector_type(4)));

__device__ inline unsigned char to_fp8(float f) {
  return (unsigned char)__hip_cvt_float_to_fp8(f, __HIP_SATFINITE, __HIP_E4M3);
}

__device__ inline void async_copy16(const void* g, void* l) {
  __builtin_amdgcn_global_load_lds((const __attribute__((address_space(1))) void*)g,
                                   (__attribute__((address_space(3))) void*)l, 16, 0, 0);
}

// ---------------------------------------------------------------------------
// Act quant: per-(row,128-block) amax -> scale -> fp8. One wave per block.
// Scales stored TRANSPOSED: St[kb][t].
// ---------------------------------------------------------------------------
__global__ void quant_x_kernel(const float* __restrict__ X, unsigned char* __restrict__ Q,
                               float* __restrict__ St, const int T, const int D) {
  const int wave = (blockIdx.x << 2) + (threadIdx.x >> 6);
  const int lane = threadIdx.x & 63;
  const int nb = D >> 7;
  const int t = wave / nb;
  const int kb = wave - t * nb;
  const size_t base = (size_t)t * D + ((size_t)kb << 7);
  const float2 v = ((const float2*)(X + base))[lane];
  float a = fmaxf(fabsf(v.x), fabsf(v.y));
#pragma unroll
  for (int off = 32; off > 0; off >>= 1) a = fmaxf(a, __shfl_xor(a, off));
  const float scale = (a == 0.f) ? 1.f : (a / 448.f);
  unsigned short pk = (unsigned short)to_fp8(v.x / scale) |
                      ((unsigned short)to_fp8(v.y / scale) << 8);
  ((unsigned short*)(Q + base))[lane] = pk;
  if (lane == 0) St[(size_t)kb * T + t] = scale;
}

// ---------------------------------------------------------------------------
// silu(h1)*h3, then per-128-block quantization.
// ---------------------------------------------------------------------------
__global__ void silu_mul_quant_kernel(const float* __restrict__ H1, const float* __restrict__ H3,
                                      unsigned char* __restrict__ Q, float* __restrict__ St,
                                      const int T, const int D) {
  const int wave = (blockIdx.x << 2) + (threadIdx.x >> 6);
  const int lane = threadIdx.x & 63;
  const int nb = D >> 7;
  const int t = wave / nb;
  const int kb = wave - t * nb;
  const size_t base = (size_t)t * D + ((size_t)kb << 7);
  const float2 v1 = ((const float2*)(H1 + base))[lane];
  const float2 v3 = ((const float2*)(H3 + base))[lane];
  const float hx = (v1.x / (1.f + expf(-v1.x))) * v3.x;
  const float hy = (v1.y / (1.f + expf(-v1.y))) * v3.y;
  float a = fmaxf(fabsf(hx), fabsf(hy));
#pragma unroll
  for (int off = 32; off > 0; off >>= 1) a = fmaxf(a, __shfl_xor(a, off));
  const float scale = (a == 0.f) ? 1.f : (a / 448.f);
  unsigned short pk = (unsigned short)to_fp8(hx / scale) |
                      ((unsigned short)to_fp8(hy / scale) << 8);
  ((unsigned short*)(Q + base))[lane] = pk;
  if (lane == 0) St[(size_t)kb * T + t] = scale;
}

// ---------------------------------------------------------------------------
// Weight convert fp32 -> fp8 (values are exactly fp8-representable).
// ---------------------------------------------------------------------------
__global__ void convert_fp8_kernel(const float4* __restrict__ W, unsigned int* __restrict__ Q,
                                   const int n4) {
  const int i = blockIdx.x * 256 + threadIdx.x;
  if (i >= n4) return;
  const float4 f = W[i];
  Q[i] = (unsigned int)to_fp8(f.x) | ((unsigned int)to_fp8(f.y) << 8) |
         ((unsigned int)to_fp8(f.z) << 16) | ((unsigned int)to_fp8(f.w) << 24);
}

// ---------------------------------------------------------------------------
// fp8 block-scaled GEMM, 256x256 tile, BK=128, 512 threads = 8 waves (2Mx4N),
// per-wave 128x64 output. Deep-pipelined 4-phase schedule per K-tile
// (T3+T4 counted vmcnt + T5 setprio), XOR-swizzled LDS (T2, both-sides via
// pre-swizzled global source + swizzled ds_read offsets).
//
// Scale handling keeps the vmcnt ledger EXACT (9 gloads/wave/tile):
//   - A row-scales staged to LDS via global_load_lds (lanes 0-7, 1 instr)
//   - B block-scales preloaded to LDS once in the prologue
// Dual-output support: blocks with blockIdx.y >= NY use the second
// (B,sB,C) set -> GEMM1+GEMM3 fused in one dispatch.
// ---------------------------------------------------------------------------
__global__ __launch_bounds__(512, 2) void gemm256_fp8_bs(
    const unsigned char* __restrict__ A, const float* __restrict__ sAt,
    const unsigned char* __restrict__ Ba, const float* __restrict__ sBa, float* __restrict__ Ca,
    const unsigned char* __restrict__ Bb, const float* __restrict__ sBb, float* __restrict__ Cb,
    const int NY, const int M, const int N, const int K) {
  __shared__ __align__(16) unsigned char As[2][256 * 128];
  __shared__ __align__(16) unsigned char Bs[2][256 * 128];
  __shared__ __align__(16) float sAs[2][256];
  __shared__ float sbl[192];  // 2 * nkb (nkb <= 86)

  const int tid = threadIdx.x;
  const int lane = tid & 63;
  const int w = tid >> 6;
  const int wm = w >> 2;           // 0..1
  const int wn = w & 3;            // 0..3
  const int wmrow = wm << 7;       // wave row base (128)
  const int wnrow = wn << 6;       // wave col base (64)
  const int row16 = lane & 15;
  const int quad = lane >> 4;
  const int nkb = K >> 7;

  int by = (int)blockIdx.y;
  const int sel = by >= NY;
  if (sel) by -= NY;
  const unsigned char* B = sel ? Bb : Ba;
  const float* sB = sel ? sBb : sBa;
  float* C = sel ? Cb : Ca;
  const int m0 = (int)blockIdx.x << 8;
  const int n0 = by << 8;

  // ---- prologue: B block-scales (2 rows x nkb) -> LDS
  {
    const float* p0 = sB + (size_t)(n0 >> 7) * nkb;
    if (tid < 2 * nkb) sbl[tid] = p0[tid];
  }

  // ---- staging addresses (per thread). LDS dest is linear; global source
  // column pre-swizzled: slot s of row r holds granule s^(r&7).
  const int srow = tid >> 3;                                // 0..63 (round 0)
  const int gcol = (((tid & 7) ^ (srow & 7)) << 4);
  const unsigned char* gA = A + (size_t)(m0 + srow) * K + gcol;
  const unsigned char* gB = B + (size_t)(n0 + srow) * K + gcol;
  const float* gSa = sAt + m0 + (w << 5) + ((lane & 7) << 2);  // lanes 0-7 only

  // swizzled read offsets: lane needs granules 2q, 2q+1 of its row
  const int off0 = (((quad << 1) ^ (row16 & 7)) << 4);
  const int off1 = off0 ^ 16;

  v4f zero = {0.f, 0.f, 0.f, 0.f};
  v4f acc[8][4];
#pragma unroll
  for (int i = 0; i < 8; ++i)
#pragma unroll
    for (int j = 0; j < 4; ++j) acc[i][j] = zero;

#define STAGE(c, kb_)                                                           \
  {                                                                             \
    const size_t koff_ = (size_t)(kb_) << 7;                                    \
    _Pragma("unroll") for (int t_ = 0; t_ < 4; ++t_)                            \
        async_copy16(gA + koff_ + ((size_t)(t_ << 6)) * K,                      \
                     &As[c][(t_ << 13) + (w << 10)]);                           \
    _Pragma("unroll") for (int t_ = 0; t_ < 4; ++t_)                            \
        async_copy16(gB + koff_ + ((size_t)(t_ << 6)) * K,                      \
                     &Bs[c][(t_ << 13) + (w << 10)]);                           \
    if (lane < 8) async_copy16(gSa + (size_t)(kb_) * M, &sAs[c][w << 5]);       \
  }

#define LDA(dst, AP, mi)                                                        \
  {                                                                             \
    const unsigned char* p_ = (AP) + ((wmrow + ((mi) << 4) + row16) << 7);      \
    const v4i lo_ = *(const v4i*)(p_ + off0);                                   \
    const v4i hi_ = *(const v4i*)(p_ + off1);                                   \
    dst = __builtin_shufflevector(lo_, hi_, 0, 1, 2, 3, 4, 5, 6, 7);            \
  }

#define LDB(dst, BP, nj)                                                        \
  {                                                                             \
    const unsigned char* p_ = (BP) + ((wnrow + ((nj) << 4) + row16) << 7);      \
    const v4i lo_ = *(const v4i*)(p_ + off0);                                   \
    const v4i hi_ = *(const v4i*)(p_ + off1);                                   \
    dst = __builtin_shufflevector(lo_, hi_, 0, 1, 2, 3, 4, 5, 6, 7);            \
  }

  // cs_i = sa(rows of frag h*4+i) * sb ; sa row = wmrow + (h*4+i)*16 + quad*4
#define LDCS(H)                                                                 \
  {                                                                             \
    const float4 s0_ = *(const float4*)(Sc + wmrow + ((H) << 6) + (quad << 2)); \
    const float4 s1_ = *(const float4*)(Sc + wmrow + ((H) << 6) + 16 + (quad << 2)); \
    const float4 s2_ = *(const float4*)(Sc + wmrow + ((H) << 6) + 32 + (quad << 2)); \
    const float4 s3_ = *(const float4*)(Sc + wmrow + ((H) << 6) + 48 + (quad << 2)); \
    cs0 = (v4f){s0_.x * sb, s0_.y * sb, s0_.z * sb, s0_.w * sb};                \
    cs1 = (v4f){s1_.x * sb, s1_.y * sb, s1_.z * sb, s1_.w * sb};                \
    cs2 = (v4f){s2_.x * sb, s2_.y * sb, s2_.z * sb, s2_.w * sb};                \
    cs3 = (v4f){s3_.x * sb, s3_.y * sb, s3_.z * sb, s3_.w * sb};                \
  }

#define MFMA1(af, bf)                                                           \
  __builtin_amdgcn_mfma_scale_f32_16x16x128_f8f6f4((af), (bf), zero, 0, 0, 0,   \
                                                   0x7f7f7f7f, 0, 0x7f7f7f7f)

#define MFMA8(H, bL, bR, jL, jR)                                                \
  {                                                                             \
    v4f p_;                                                                     \
    p_ = MFMA1(a0, bL); acc[(H)*4 + 0][jL] += cs0 * p_;                         \
    p_ = MFMA1(a0, bR); acc[(H)*4 + 0][jR] += cs0 * p_;                         \
    p_ = MFMA1(a1, bL); acc[(H)*4 + 1][jL] += cs1 * p_;                         \
    p_ = MFMA1(a1, bR); acc[(H)*4 + 1][jR] += cs1 * p_;                         \
    p_ = MFMA1(a2, bL); acc[(H)*4 + 2][jL] += cs2 * p_;                         \
    p_ = MFMA1(a2, bR); acc[(H)*4 + 2][jR] += cs2 * p_;                         \
    p_ = MFMA1(a3, bL); acc[(H)*4 + 3][jL] += cs3 * p_;                         \
    p_ = MFMA1(a3, bR); acc[(H)*4 + 3][jR] += cs3 * p_;                         \
  }

#define PHASE_PRE                                                               \
  __builtin_amdgcn_s_barrier();                                                 \
  asm volatile("s_waitcnt lgkmcnt(0)" ::: "memory");                            \
  __builtin_amdgcn_sched_barrier(0);                                            \
  __builtin_amdgcn_s_setprio(1);

#define PHASE_POST                                                              \
  __builtin_amdgcn_s_setprio(0);                                                \
  __builtin_amdgcn_s_barrier();

  __syncthreads();  // sbl visible to all waves

  STAGE(0, 0);

  const int sbi = (wn >> 1) * nkb;

  for (int kb = 0; kb < nkb; ++kb) {
    const int cur = kb & 1;
    // issue next tile's staging into the buffer freed at tile kb-1's end,
    // then drain THIS tile's loads (issued one full tile ago): vmcnt(9).
    if (kb + 1 < nkb) {
      STAGE(cur ^ 1, kb + 1);
      asm volatile("s_waitcnt vmcnt(9)" ::: "memory");
    } else {
      asm volatile("s_waitcnt vmcnt(0)" ::: "memory");
    }
    __builtin_amdgcn_s_barrier();
    __builtin_amdgcn_sched_barrier(0);

    const unsigned char* Ac = As[cur];
    const unsigned char* Bc = Bs[cur];
    const float* Sc = sAs[cur];
    const float sb = sbl[sbi + kb];
    v8i a0, a1, a2, a3, b0, b1, b2, b3;
    v4f cs0, cs1, cs2, cs3;

    // ---- P0: M-half 0, N-half 0
    LDA(a0, Ac, 0); LDA(a1, Ac, 1); LDA(a2, Ac, 2); LDA(a3, Ac, 3);
    LDB(b0, Bc, 0); LDB(b1, Bc, 1);
    LDCS(0);
    PHASE_PRE;
    MFMA8(0, b0, b1, 0, 1);
    PHASE_POST;
    // ---- P1: M-half 0, N-half 1
    LDB(b2, Bc, 2); LDB(b3, Bc, 3);
    PHASE_PRE;
    MFMA8(0, b2, b3, 2, 3);
    PHASE_POST;
    // ---- P2: M-half 1, N-half 0
    LDA(a0, Ac, 4); LDA(a1, Ac, 5); LDA(a2, Ac, 6); LDA(a3, Ac, 7);
    LDCS(1);
    PHASE_PRE;
    MFMA8(1, b0, b1, 0, 1);
    PHASE_POST;
    // ---- P3: M-half 1, N-half 1
    PHASE_PRE;
    MFMA8(1, b2, b3, 2, 3);
    PHASE_POST;
  }

#undef STAGE
#undef LDA
#undef LDB
#undef LDCS
#undef MFMA1
#undef MFMA8
#undef PHASE_PRE
#undef PHASE_POST

  // epilogue: C/D layout col=lane&15, row=quad*4+reg
#pragma unroll
  for (int mi = 0; mi < 8; ++mi) {
    const size_t rb = (size_t)(m0 + wmrow + (mi << 4) + (quad << 2));
#pragma unroll
    for (int r = 0; r < 4; ++r) {
      float* crow = C + (rb + r) * N + n0 + wnrow + row16;
#pragma unroll
      for (int nj = 0; nj < 4; ++nj) crow[nj << 4] = acc[mi][nj][r];
    }
  }
}

extern "C" void kernel_launch(void* const* d_in, const int* in_sizes, int n_in,
                              void* d_out, int out_size, void* d_ws, size_t ws_size,
                              hipStream_t stream) {
  const float* x   = (const float*)d_in[0];
  const float* w1q = (const float*)d_in[1];
  const float* w1s = (const float*)d_in[2];
  const float* w2q = (const float*)d_in[3];
  const float* w2s = (const float*)d_in[4];
  const float* w3q = (const float*)d_in[5];
  const float* w3s = (const float*)d_in[6];

  unsigned char* ws = (unsigned char*)d_ws;
  const size_t SZ_QX = (size_t)T_DIM * D_DIM;          // 8,388,608
  const size_t SZ_W  = (size_t)I_DIM * D_DIM;          // 45,088,768 (per weight)
  const size_t SZ_QH = (size_t)T_DIM * I_DIM;          // 22,544,384
  const size_t SZ_SX = (size_t)(D_DIM / 128) * T_DIM * 4;
  const size_t SZ_SH = (size_t)(I_DIM / 128) * T_DIM * 4;
  const size_t SZ_H  = (size_t)T_DIM * I_DIM * 4;      // 90,177,536

  unsigned char* qx   = ws;             ws += SZ_QX;
  unsigned char* w1q8 = ws;             ws += SZ_W;
  unsigned char* w3q8 = ws;             ws += SZ_W;
  unsigned char* w2q8 = ws;             ws += SZ_W;
  unsigned char* qh   = ws;             ws += SZ_QH;
  float* sxt = (float*)ws;              ws += SZ_SX;
  float* sht = (float*)ws;              ws += SZ_SH;
  float* h1  = (float*)ws;              ws += SZ_H;
  float* h3  = (float*)ws;              ws += SZ_H;

  // 1. quantize x
  quant_x_kernel<<<(T_DIM * (D_DIM / 128)) / 4, 256, 0, stream>>>(x, qx, sxt, T_DIM, D_DIM);

  // 2. convert weights fp32 -> fp8 (exact)
  const int n4w = (int)(SZ_W / 4);
  convert_fp8_kernel<<<(n4w + 255) / 256, 256, 0, stream>>>((const float4*)w1q, (unsigned int*)w1q8, n4w);
  convert_fp8_kernel<<<(n4w + 255) / 256, 256, 0, stream>>>((const float4*)w3q, (unsigned int*)w3q8, n4w);
  convert_fp8_kernel<<<(n4w + 255) / 256, 256, 0, stream>>>((const float4*)w2q, (unsigned int*)w2q8, n4w);

  // 3. GEMM1 + GEMM3 fused in one dispatch: grid (8, 86); by<43 -> w1/h1
  dim3 g13(T_DIM / 256, 2 * (I_DIM / 256));
  gemm256_fp8_bs<<<g13, 512, 0, stream>>>(qx, sxt,
                                          w1q8, w1s, h1,
                                          w3q8, w3s, h3,
                                          I_DIM / 256, T_DIM, I_DIM, D_DIM);

  // 4. h = silu(h1)*h3, quantized per 128-block
  silu_mul_quant_kernel<<<(T_DIM * (I_DIM / 128)) / 4, 256, 0, stream>>>(h1, h3, qh, sht, T_DIM, I_DIM);

  // 5. GEMM2: [2048,11008] x [4096,11008]^T -> out
  dim3 g2(T_DIM / 256, D_DIM / 256);
  gemm256_fp8_bs<<<g2, 512, 0, stream>>>(qh, sht,
                                         w2q8, w2s, (float*)d_out,
                                         w2q8, w2s, (float*)d_out,
                                         D_DIM / 256, T_DIM, D_DIM, I_DIM);

  (void)in_sizes; (void)n_in; (void)out_size; (void)ws_size;
}

// Round 3
// 1042.996 us; speedup vs baseline: 1.1595x; 1.1595x over previous
//
#include <hip/hip_runtime.h>
#include <hip/hip_fp8.h>
#include <hip/hip_fp16.h>

#define T_DIM 2048
#define D_DIM 4096
#define I_DIM 11008

typedef int v8i __attribute__((ext_vector_type(8)));
typedef int v4i __attribute__((ext_vector_type(4)));
typedef float v4f __attribute__((ext_vector_type(4)));

__device__ inline unsigned char to_fp8(float f) {
  return (unsigned char)__hip_cvt_float_to_fp8(f, __HIP_SATFINITE, __HIP_E4M3);
}

__device__ inline void async_copy16(const void* g, void* l) {
  __builtin_amdgcn_global_load_lds((const __attribute__((address_space(1))) void*)g,
                                   (__attribute__((address_space(3))) void*)l, 16, 0, 0);
}

// ---------------------------------------------------------------------------
// Act quant: per-(row,128-block) amax -> scale -> fp8. One wave per block.
// Scales stored TRANSPOSED: St[kb][t].
// ---------------------------------------------------------------------------
__global__ void quant_x_kernel(const float* __restrict__ X, unsigned char* __restrict__ Q,
                               float* __restrict__ St, const int T, const int D) {
  const int wave = (blockIdx.x << 2) + (threadIdx.x >> 6);
  const int lane = threadIdx.x & 63;
  const int nb = D >> 7;
  const int t = wave / nb;
  const int kb = wave - t * nb;
  const size_t base = (size_t)t * D + ((size_t)kb << 7);
  const float2 v = ((const float2*)(X + base))[lane];
  float a = fmaxf(fabsf(v.x), fabsf(v.y));
#pragma unroll
  for (int off = 32; off > 0; off >>= 1) a = fmaxf(a, __shfl_xor(a, off));
  const float scale = (a == 0.f) ? 1.f : (a / 448.f);
  unsigned short pk = (unsigned short)to_fp8(v.x / scale) |
                      ((unsigned short)to_fp8(v.y / scale) << 8);
  ((unsigned short*)(Q + base))[lane] = pk;
  if (lane == 0) St[(size_t)kb * T + t] = scale;
}

// ---------------------------------------------------------------------------
// silu(h1)*h3 (h stored fp16 by GEMM1/3 epilogue), then per-128-block quant.
// ---------------------------------------------------------------------------
__global__ void silu_mul_quant_kernel(const __half* __restrict__ H1, const __half* __restrict__ H3,
                                      unsigned char* __restrict__ Q, float* __restrict__ St,
                                      const int T, const int D) {
  const int wave = (blockIdx.x << 2) + (threadIdx.x >> 6);
  const int lane = threadIdx.x & 63;
  const int nb = D >> 7;
  const int t = wave / nb;
  const int kb = wave - t * nb;
  const size_t base = (size_t)t * D + ((size_t)kb << 7);
  const float2 v1 = __half22float2(((const __half2*)(H1 + base))[lane]);
  const float2 v3 = __half22float2(((const __half2*)(H3 + base))[lane]);
  const float hx = (v1.x / (1.f + expf(-v1.x))) * v3.x;
  const float hy = (v1.y / (1.f + expf(-v1.y))) * v3.y;
  float a = fmaxf(fabsf(hx), fabsf(hy));
#pragma unroll
  for (int off = 32; off > 0; off >>= 1) a = fmaxf(a, __shfl_xor(a, off));
  const float scale = (a == 0.f) ? 1.f : (a / 448.f);
  unsigned short pk = (unsigned short)to_fp8(hx / scale) |
                      ((unsigned short)to_fp8(hy / scale) << 8);
  ((unsigned short*)(Q + base))[lane] = pk;
  if (lane == 0) St[(size_t)kb * T + t] = scale;
}

// ---------------------------------------------------------------------------
// Weight convert fp32 -> fp8 for all three weights, grid-stride (2048 blocks).
// ---------------------------------------------------------------------------
__global__ void convert3_fp8_kernel(const float4* __restrict__ W1, const float4* __restrict__ W3,
                                    const float4* __restrict__ W2, unsigned int* __restrict__ Q1,
                                    unsigned int* __restrict__ Q3, unsigned int* __restrict__ Q2,
                                    const int n4) {
  const int stride = gridDim.x * blockDim.x;
  const int total = 3 * n4;
  for (int i = blockIdx.x * blockDim.x + threadIdx.x; i < total; i += stride) {
    const float4* src;
    unsigned int* dst;
    int j = i;
    if (j < n4) { src = W1; dst = Q1; }
    else if (j < 2 * n4) { src = W3; dst = Q3; j -= n4; }
    else { src = W2; dst = Q2; j -= 2 * n4; }
    const float4 f = src[j];
    dst[j] = (unsigned int)to_fp8(f.x) | ((unsigned int)to_fp8(f.y) << 8) |
             ((unsigned int)to_fp8(f.z) << 16) | ((unsigned int)to_fp8(f.w) << 24);
  }
}

// ---------------------------------------------------------------------------
// fp8 block-scaled GEMM. BM x 256 tile (BM = MI*32), BK=128, 512 threads =
// 8 waves (2M x 4N), per-wave (MI*16) x 64 output.
// Round-3 structure: 2 barriers per K-tile, COUNTED vmcnt (never drain-0 in
// steady state), raw s_barrier (no implicit drain), sched_barrier(0) pins,
// compiler-scheduled ds_read/MFMA interleave within the tile region.
// XOR-swizzled LDS (pre-swizzled global source + swizzled ds_read offsets).
// vmcnt ledger exact: MI/2 (A) + 4 (B) + 1 (A-scales) gloads per wave/tile.
// Dual-output: blocks with blockIdx.y >= NY use the (Bb,sBb,Cb) set.
// ---------------------------------------------------------------------------
template <int MI, typename CT>
__global__ __launch_bounds__(512, 2) void gemm256_fp8_bs(
    const unsigned char* __restrict__ A, const float* __restrict__ sAt,
    const unsigned char* __restrict__ Ba, const float* __restrict__ sBa, CT* __restrict__ Ca,
    const unsigned char* __restrict__ Bb, const float* __restrict__ sBb, CT* __restrict__ Cb,
    const int NY, const int M, const int N, const int K) {
  constexpr int BM = MI * 32;      // 256 (MI=8) or 128 (MI=4)
  constexpr int AT = MI / 2;       // A staging instrs per wave (4 or 2)
  __shared__ __align__(16) unsigned char As[2][BM * 128];
  __shared__ __align__(16) unsigned char Bs[2][256 * 128];
  __shared__ __align__(16) float sAs[2][BM];
  __shared__ float sbl[192];

  const int tid = threadIdx.x;
  const int lane = tid & 63;
  const int w = tid >> 6;
  const int wm = w >> 2;                 // 0..1
  const int wn = w & 3;                  // 0..3
  const int wmrow = wm * (MI << 4);      // wave row base
  const int wnrow = wn << 6;             // wave col base
  const int row16 = lane & 15;
  const int quad = lane >> 4;
  const int nkb = K >> 7;

  int by = (int)blockIdx.y;
  const int sel = by >= NY;
  if (sel) by -= NY;
  const unsigned char* B = sel ? Bb : Ba;
  const float* sB = sel ? sBb : sBa;
  CT* C = sel ? Cb : Ca;
  const int m0 = (int)blockIdx.x * BM;
  const int n0 = by << 8;

  // ---- prologue: B block-scales (2 rows x nkb) -> LDS
  {
    const float* p0 = sB + (size_t)(n0 >> 7) * nkb;
    if (tid < 2 * nkb) sbl[tid] = p0[tid];
  }

  // ---- staging addresses. LDS dest linear; global source column
  // pre-swizzled so LDS slot s of row r holds global granule s^(r&7).
  const int srow = tid >> 3;  // 0..63
  const int gcol = (((tid & 7) ^ (srow & 7)) << 4);
  const unsigned char* gA = A + (size_t)(m0 + srow) * K + gcol;
  const unsigned char* gB = B + (size_t)(n0 + srow) * K + gcol;
  const float* gSa = sAt + m0 + w * (BM / 8) + (lane << 2);  // lanes < BM/32

  // swizzled read offsets: lane needs granules 2q, 2q+1 of its row
  const int off0 = (((quad << 1) ^ (row16 & 7)) << 4);
  const int off1 = off0 ^ 16;

  v4f zero = {0.f, 0.f, 0.f, 0.f};
  v4f acc[MI][4];
#pragma unroll
  for (int i = 0; i < MI; ++i)
#pragma unroll
    for (int j = 0; j < 4; ++j) acc[i][j] = zero;

#define STAGE(c, kb_)                                                           \
  {                                                                             \
    const size_t koff_ = (size_t)(kb_) << 7;                                    \
    _Pragma("unroll") for (int t_ = 0; t_ < AT; ++t_)                           \
        async_copy16(gA + koff_ + ((size_t)(t_ << 6)) * K,                      \
                     &As[c][(t_ << 13) + (w << 10)]);                           \
    _Pragma("unroll") for (int t_ = 0; t_ < 4; ++t_)                            \
        async_copy16(gB + koff_ + ((size_t)(t_ << 6)) * K,                      \
                     &Bs[c][(t_ << 13) + (w << 10)]);                           \
    if (lane < BM / 32) async_copy16(gSa + (size_t)(kb_) * M, &sAs[c][w * (BM / 8)]); \
  }

#define LDA(dst, AP, mi)                                                        \
  {                                                                             \
    const unsigned char* p_ = (AP) + ((wmrow + ((mi) << 4) + row16) << 7);      \
    const v4i lo_ = *(const v4i*)(p_ + off0);                                   \
    const v4i hi_ = *(const v4i*)(p_ + off1);                                   \
    dst = __builtin_shufflevector(lo_, hi_, 0, 1, 2, 3, 4, 5, 6, 7);            \
  }

#define LDB(dst, BP, nj)                                                        \
  {                                                                             \
    const unsigned char* p_ = (BP) + ((wnrow + ((nj) << 4) + row16) << 7);      \
    const v4i lo_ = *(const v4i*)(p_ + off0);                                   \
    const v4i hi_ = *(const v4i*)(p_ + off1);                                   \
    dst = __builtin_shufflevector(lo_, hi_, 0, 1, 2, 3, 4, 5, 6, 7);            \
  }

#define LDCS(H)                                                                 \
  {                                                                             \
    const float4 s0_ = *(const float4*)(Sc + wmrow + ((H) << 6) + (quad << 2)); \
    const float4 s1_ = *(const float4*)(Sc + wmrow + ((H) << 6) + 16 + (quad << 2)); \
    const float4 s2_ = *(const float4*)(Sc + wmrow + ((H) << 6) + 32 + (quad << 2)); \
    const float4 s3_ = *(const float4*)(Sc + wmrow + ((H) << 6) + 48 + (quad << 2)); \
    cs0 = (v4f){s0_.x * sb, s0_.y * sb, s0_.z * sb, s0_.w * sb};                \
    cs1 = (v4f){s1_.x * sb, s1_.y * sb, s1_.z * sb, s1_.w * sb};                \
    cs2 = (v4f){s2_.x * sb, s2_.y * sb, s2_.z * sb, s2_.w * sb};                \
    cs3 = (v4f){s3_.x * sb, s3_.y * sb, s3_.z * sb, s3_.w * sb};                \
  }

#define MFMA1(af, bf)                                                           \
  __builtin_amdgcn_mfma_scale_f32_16x16x128_f8f6f4((af), (bf), zero, 0, 0, 0,   \
                                                   0x7f7f7f7f, 0, 0x7f7f7f7f)

#define MFMA8(H, bL, bR, jL, jR)                                                \
  {                                                                             \
    v4f p_;                                                                     \
    p_ = MFMA1(a0, bL); acc[(H)*4 + 0][jL] += cs0 * p_;                         \
    p_ = MFMA1(a0, bR); acc[(H)*4 + 0][jR] += cs0 * p_;                         \
    p_ = MFMA1(a1, bL); acc[(H)*4 + 1][jL] += cs1 * p_;                         \
    p_ = MFMA1(a1, bR); acc[(H)*4 + 1][jR] += cs1 * p_;                         \
    p_ = MFMA1(a2, bL); acc[(H)*4 + 2][jL] += cs2 * p_;                         \
    p_ = MFMA1(a2, bR); acc[(H)*4 + 2][jR] += cs2 * p_;                         \
    p_ = MFMA1(a3, bL); acc[(H)*4 + 3][jL] += cs3 * p_;                         \
    p_ = MFMA1(a3, bR); acc[(H)*4 + 3][jR] += cs3 * p_;                         \
  }

  __syncthreads();  // sbl visible (full drain once, prologue only)

  STAGE(0, 0);

  const int sbi = (wn >> 1) * nkb;

  for (int kb = 0; kb < nkb; ++kb) {
    const int cur = kb & 1;
    // Issue next tile's staging, then wait only for THIS tile's loads
    // (issued one full tile ago): counted vmcnt, never 0 in steady state.
    if (kb + 1 < nkb) {
      STAGE(cur ^ 1, kb + 1);
      if constexpr (MI == 8) {
        asm volatile("s_waitcnt vmcnt(9)" ::: "memory");
      } else {
        asm volatile("s_waitcnt vmcnt(7)" ::: "memory");
      }
    } else {
      asm volatile("s_waitcnt vmcnt(0)" ::: "memory");
    }
    __builtin_amdgcn_s_barrier();
    __builtin_amdgcn_sched_barrier(0);

    const unsigned char* Ac = As[cur];
    const unsigned char* Bc = Bs[cur];
    const float* Sc = sAs[cur];
    const float sb = sbl[sbi + kb];
    v8i a0, a1, a2, a3, b0, b1, b2, b3;
    v4f cs0, cs1, cs2, cs3;

    LDB(b0, Bc, 0); LDB(b1, Bc, 1); LDB(b2, Bc, 2); LDB(b3, Bc, 3);

    // sub-phase 0: M-frags 0-3 (no barriers inside the tile; compiler
    // interleaves ds_read / MFMA / scale-FMA with fine lgkmcnt)
    LDA(a0, Ac, 0); LDA(a1, Ac, 1); LDA(a2, Ac, 2); LDA(a3, Ac, 3);
    LDCS(0);
    MFMA8(0, b0, b1, 0, 1);
    MFMA8(0, b2, b3, 2, 3);

    if constexpr (MI == 8) {
      // sub-phase 1: M-frags 4-7 (reuse a-regs)
      LDA(a0, Ac, 4); LDA(a1, Ac, 5); LDA(a2, Ac, 6); LDA(a3, Ac, 7);
      LDCS(1);
      MFMA8(1, b0, b1, 0, 1);
      MFMA8(1, b2, b3, 2, 3);
    }

    asm volatile("s_waitcnt lgkmcnt(0)" ::: "memory");
    __builtin_amdgcn_s_barrier();       // all waves done reading buf cur
    __builtin_amdgcn_sched_barrier(0);  // pin: next STAGE must not hoist above
  }

#undef STAGE
#undef LDA
#undef LDB
#undef LDCS
#undef MFMA1
#undef MFMA8

  // epilogue: C/D layout col=lane&15, row=quad*4+reg
#pragma unroll
  for (int mi = 0; mi < MI; ++mi) {
    const size_t rb = (size_t)(m0 + wmrow + (mi << 4) + (quad << 2));
#pragma unroll
    for (int r = 0; r < 4; ++r) {
      CT* crow = C + (rb + r) * N + n0 + wnrow + row16;
#pragma unroll
      for (int nj = 0; nj < 4; ++nj) crow[nj << 4] = (CT)acc[mi][nj][r];
    }
  }
}

extern "C" void kernel_launch(void* const* d_in, const int* in_sizes, int n_in,
                              void* d_out, int out_size, void* d_ws, size_t ws_size,
                              hipStream_t stream) {
  const float* x   = (const float*)d_in[0];
  const float* w1q = (const float*)d_in[1];
  const float* w1s = (const float*)d_in[2];
  const float* w2q = (const float*)d_in[3];
  const float* w2s = (const float*)d_in[4];
  const float* w3q = (const float*)d_in[5];
  const float* w3s = (const float*)d_in[6];

  unsigned char* ws = (unsigned char*)d_ws;
  const size_t SZ_QX = (size_t)T_DIM * D_DIM;          // 8,388,608
  const size_t SZ_W  = (size_t)I_DIM * D_DIM;          // 45,088,768 (per weight)
  const size_t SZ_QH = (size_t)T_DIM * I_DIM;          // 22,544,384
  const size_t SZ_SX = (size_t)(D_DIM / 128) * T_DIM * 4;
  const size_t SZ_SH = (size_t)(I_DIM / 128) * T_DIM * 4;
  const size_t SZ_H  = (size_t)T_DIM * I_DIM * 2;      // fp16 now: 45,088,768

  unsigned char* qx   = ws;             ws += SZ_QX;
  unsigned char* w1q8 = ws;             ws += SZ_W;
  unsigned char* w3q8 = ws;             ws += SZ_W;
  unsigned char* w2q8 = ws;             ws += SZ_W;
  unsigned char* qh   = ws;             ws += SZ_QH;
  float* sxt = (float*)ws;              ws += SZ_SX;
  float* sht = (float*)ws;              ws += SZ_SH;
  __half* h1 = (__half*)ws;             ws += SZ_H;
  __half* h3 = (__half*)ws;             ws += SZ_H;

  // 1. quantize x
  quant_x_kernel<<<(T_DIM * (D_DIM / 128)) / 4, 256, 0, stream>>>(x, qx, sxt, T_DIM, D_DIM);

  // 2. convert all three weights fp32 -> fp8, grid-stride
  const int n4w = (int)(SZ_W / 4);
  convert3_fp8_kernel<<<2048, 256, 0, stream>>>((const float4*)w1q, (const float4*)w3q,
                                                (const float4*)w2q, (unsigned int*)w1q8,
                                                (unsigned int*)w3q8, (unsigned int*)w2q8, n4w);

  // 3. GEMM1 + GEMM3 fused: grid (8, 86); by<43 -> w1/h1. fp16 output.
  dim3 g13(T_DIM / 256, 2 * (I_DIM / 256));
  gemm256_fp8_bs<8, __half><<<g13, 512, 0, stream>>>(qx, sxt,
                                                     w1q8, w1s, h1,
                                                     w3q8, w3s, h3,
                                                     I_DIM / 256, T_DIM, I_DIM, D_DIM);

  // 4. h = silu(h1)*h3 (fp16 in), quantized per 128-block
  silu_mul_quant_kernel<<<(T_DIM * (I_DIM / 128)) / 4, 256, 0, stream>>>(h1, h3, qh, sht, T_DIM, I_DIM);

  // 5. GEMM2: 128x256 tiles -> grid (16,16) = 256 blocks = one full round
  dim3 g2(T_DIM / 128, D_DIM / 256);
  gemm256_fp8_bs<4, float><<<g2, 512, 0, stream>>>(qh, sht,
                                                   w2q8, w2s, (float*)d_out,
                                                   w2q8, w2s, (float*)d_out,
                                                   D_DIM / 256, T_DIM, D_DIM, I_DIM);

  (void)in_sizes; (void)n_in; (void)out_size; (void)ws_size;
}